// Round 12
// baseline (305.896 us; speedup 1.0000x reference)
//
#include <hip/hip_runtime.h>
#include <hip/hip_bf16.h>

#define B_ 1024
#define IN_ 512
#define OUT_ 512
#define NIP (IN_ / 2)            // 256 i-pairs
#define KSPLIT 4
#define IP_PER (NIP / KSPLIT)    // 64 i-pairs per k-slice
#define BTILE 64
#define PF_FLOATS ((size_t)OUT_ * NIP * 12)   // 6 MB folded params
// ws: pf [OUT][NIP][12] (6 MB) | xs [NIP][B][4]={x0,x1,s0,s1} (4 MB)

typedef float v2f __attribute__((ext_vector_type(2)));
#define PKFMA(a, b, c) __builtin_elementwise_fma((v2f)(a), (v2f)(b), (v2f)(c))

__device__ __forceinline__ float fast_exp2(float x) {
#if __has_builtin(__builtin_amdgcn_exp2f)
    return __builtin_amdgcn_exp2f(x);
#else
    return __exp2f(x);
#endif
}
__device__ __forceinline__ float fast_log2(float x) {
#if __has_builtin(__builtin_amdgcn_logf)
    return __builtin_amdgcn_logf(x);
#else
    return __log2f(x);
#endif
}
__device__ __forceinline__ float fast_cos_rev(float x) {  // cos(2*pi*x), revolutions
#if __has_builtin(__builtin_amdgcn_cosf)
    return __builtin_amdgcn_cosf(x);
#else
    return __cosf(x * 6.2831853071795864f);
#endif
}
__device__ __forceinline__ float fast_rcp(float x) {
#if __has_builtin(__builtin_amdgcn_rcpf)
    return __builtin_amdgcn_rcpf(x);
#else
    return 1.0f / x;
#endif
}

// ---- Pass A: fold raw params -> pf[o][ip][12] = {a0,a1,b0,b1, c0,c1,d0,d1, lw0,lw1,w0,w1}
__global__ __launch_bounds__(256) void fold_kernel(
    const float* __restrict__ S, const float* __restrict__ T,
    const float* __restrict__ F, const float* __restrict__ W,
    const float* __restrict__ Wc, float* __restrict__ pf)
{
    const int idx = blockIdx.x * 256 + threadIdx.x;   // 131072 = 512 o * 256 ip
    const int ip = idx & (NIP - 1);
    const int o  = idx >> 8;
    const float GK = 0.8493218002880191f;             // sqrt(0.5*log2(e))
    const size_t g = (size_t)o * IN_ + 2 * ip;
    const float2 s = *(const float2*)(S + g);
    const float2 t = *(const float2*)(T + g);
    const float2 f = *(const float2*)(F + g);
    const float2 w = *(const float2*)(W + g);
    const float2 c = *(const float2*)(Wc + g);
    const float sa[2] = { s.x, s.y }, ta[2] = { t.x, t.y }, fa[2] = { f.x, f.y };
    const float wa[2] = { w.x, w.y }, ca[2] = { c.x, c.y };
    float a[2], b[2], cc[2], d[2], lw[2];
    #pragma unroll
    for (int j = 0; j < 2; ++j) {
        const float rs = fast_rcp(sa[j]);
        a[j]  = fa[j] * rs;                                  // revolutions per x
        b[j]  = -a[j] * ta[j] + (ca[j] < 0.0f ? 0.5f : 0.0f); // phase + sign(Wc)
        cc[j] = rs * GK;
        d[j]  = -ta[j] * rs * GK;
        lw[j] = fast_log2(fabsf(ca[j]));                     // log2|Wc|
    }
    float* p = pf + ((size_t)o * NIP + ip) * 12;
    ((float4*)p)[0] = make_float4(a[0],  a[1],  b[0],  b[1]);
    ((float4*)p)[1] = make_float4(cc[0], cc[1], d[0],  d[1]);
    ((float4*)p)[2] = make_float4(lw[0], lw[1], wa[0], wa[1]);
}

// ---- Pass B: transpose + silu x -> xs[ip][b][4] = {x0, x1, silu0, silu1}
__global__ __launch_bounds__(256) void xpose_kernel(
    const float* __restrict__ x, float* __restrict__ xs)
{
    const int idx = blockIdx.x * 256 + threadIdx.x;   // 262144 = 1024 b * 256 ip
    const int ip = idx & (NIP - 1);
    const int b  = idx >> 8;
    const float LOG2E = 1.4426950408889634f;
    const float2 v = *(const float2*)(x + (size_t)b * IN_ + 2 * ip);  // coalesced
    const float s0 = v.x * fast_rcp(1.0f + fast_exp2(-v.x * LOG2E));
    const float s1 = v.y * fast_rcp(1.0f + fast_exp2(-v.y * LOG2E));
    *(float4*)(xs + ((size_t)ip * B_ + b) * 4) = make_float4(v.x, v.y, s0, s1);
}

// ---- Main: no LDS, no barriers. Wave = 64 b-lanes x 2 o's; params via
// lane-invariant VMEM (VGPR-direct broadcast), x/silu via coalesced b128.
__global__ __launch_bounds__(256, 6) void chirplet_main(
    const float* __restrict__ pf, const float* __restrict__ xs,
    const float* __restrict__ bias, float* __restrict__ out)
{
    const int tid  = threadIdx.x;
    const int wave = tid >> 6;
    const int lane = tid & 63;
    const int o0  = (blockIdx.x * 4 + wave) * 2;          // o pair {o0, o0+1}
    const int b   = blockIdx.y * BTILE + lane;
    const int ip0 = blockIdx.z * IP_PER;

    const float* p0 = pf + ((size_t)o0 * NIP + ip0) * 12;        // lane-invariant
    const float* p1 = p0 + (size_t)NIP * 12;
    const float* xp = xs + ((size_t)ip0 * B_ + b) * 4;           // lane-variant

    v2f acc0 = {0.f, 0.f}, acc1 = {0.f, 0.f};

    #pragma unroll 2
    for (int ip = 0; ip < IP_PER; ++ip) {
        const float4 xsv = *(const float4*)(xp + (size_t)ip * (B_ * 4));
        const float4 qa0 = ((const float4*)(p0 + ip * 12))[0];
        const float4 qb0 = ((const float4*)(p0 + ip * 12))[1];
        const float4 qc0 = ((const float4*)(p0 + ip * 12))[2];
        const float4 qa1 = ((const float4*)(p1 + ip * 12))[0];
        const float4 qb1 = ((const float4*)(p1 + ip * 12))[1];
        const float4 qc1 = ((const float4*)(p1 + ip * 12))[2];
        const v2f xk = { xsv.x, xsv.y };
        const v2f sk = { xsv.z, xsv.w };

        {   // o0
            v2f rev = PKFMA(((v2f){qa0.x, qa0.y}), xk, ((v2f){qa0.z, qa0.w}));
            v2f u   = PKFMA(((v2f){qb0.x, qb0.y}), xk, ((v2f){qb0.z, qb0.w}));
            v2f g   = PKFMA(-u, u, ((v2f){qc0.x, qc0.y}));
            v2f co, e;
            co.x = fast_cos_rev(rev.x);  co.y = fast_cos_rev(rev.y);
            e.x  = fast_exp2(g.x);       e.y  = fast_exp2(g.y);
            acc0 = PKFMA(co, e, acc0);
            acc0 = PKFMA(sk, ((v2f){qc0.z, qc0.w}), acc0);
        }
        {   // o1
            v2f rev = PKFMA(((v2f){qa1.x, qa1.y}), xk, ((v2f){qa1.z, qa1.w}));
            v2f u   = PKFMA(((v2f){qb1.x, qb1.y}), xk, ((v2f){qb1.z, qb1.w}));
            v2f g   = PKFMA(-u, u, ((v2f){qc1.x, qc1.y}));
            v2f co, e;
            co.x = fast_cos_rev(rev.x);  co.y = fast_cos_rev(rev.y);
            e.x  = fast_exp2(g.x);       e.y  = fast_exp2(g.y);
            acc1 = PKFMA(co, e, acc1);
            acc1 = PKFMA(sk, ((v2f){qc1.z, qc1.w}), acc1);
        }
    }

    float r0 = acc0.x + acc0.y;
    float r1 = acc1.x + acc1.y;
    if (blockIdx.z == 0) { r0 += bias[o0]; r1 += bias[o0 + 1]; }
    float* dst = &out[(size_t)b * OUT_ + o0];
#if defined(__HIP_DEVICE_COMPILE__)
    unsafeAtomicAdd(dst,     r0);   // HW global_atomic_add_f32
    unsafeAtomicAdd(dst + 1, r1);
#else
    atomicAdd(dst,     r0);
    atomicAdd(dst + 1, r1);
#endif
}

extern "C" void kernel_launch(void* const* d_in, const int* in_sizes, int n_in,
                              void* d_out, int out_size, void* d_ws, size_t ws_size,
                              hipStream_t stream) {
    const float* x    = (const float*)d_in[0];
    const float* W    = (const float*)d_in[1];
    const float* Wc   = (const float*)d_in[2];
    const float* S    = (const float*)d_in[3];
    const float* T    = (const float*)d_in[4];
    const float* F    = (const float*)d_in[5];
    const float* bias = (const float*)d_in[6];
    float* out = (float*)d_out;

    float* pf = (float*)d_ws;                 // 6 MB folded params
    float* xs = pf + PF_FLOATS;               // 4 MB transposed x+silu

    // out is poisoned before every launch; atomics need zeroed destination
    hipMemsetAsync(out, 0, (size_t)out_size * sizeof(float), stream);

    fold_kernel<<<(OUT_ * NIP) / 256, 256, 0, stream>>>(S, T, F, W, Wc, pf);
    xpose_kernel<<<(B_ * NIP) / 256, 256, 0, stream>>>(x, xs);

    dim3 grid(OUT_ / 8, B_ / BTILE, KSPLIT);  // 64 x 16 x 4 = 4096 blocks
    chirplet_main<<<grid, 256, 0, stream>>>(pf, xs, bias, out);
}

// Round 13
// 131.282 us; speedup vs baseline: 2.3301x; 2.3301x over previous
//
#include <hip/hip_runtime.h>
#include <hip/hip_bf16.h>

#define B_ 1024
#define IN_ 512
#define OUT_ 512
#define BTILE 64
#define OTILE 32
#define ITILE 8
#define KSPLIT 16
#define KCHUNK (IN_ / KSPLIT)          // 32 i's per block
#define NCHUNKS (KCHUNK / ITILE)       // 4 staging chunks
#define P4STRIDE 128  // 32 o * 4 words; b128 writes even 8-phase (free); reads 2-way (free)
#define P2STRIDE 64   // 32 o * 2 words; reads conflict-free; b64 writes 4-phase min (free)
#define XSTRIDE 68    // BTILE + 4 pad; staging writes exactly 2-way (free)

typedef float v2f __attribute__((ext_vector_type(2)));
#define PKFMA(a, b, c) __builtin_elementwise_fma((v2f)(a), (v2f)(b), (v2f)(c))

__device__ __forceinline__ float fast_exp2(float x) {
#if __has_builtin(__builtin_amdgcn_exp2f)
    return __builtin_amdgcn_exp2f(x);
#else
    return __exp2f(x);
#endif
}
__device__ __forceinline__ float fast_log2(float x) {
#if __has_builtin(__builtin_amdgcn_logf)
    return __builtin_amdgcn_logf(x);
#else
    return __log2f(x);
#endif
}
__device__ __forceinline__ float fast_cos_rev(float x) {  // cos(2*pi*x), revolutions
#if __has_builtin(__builtin_amdgcn_cosf)
    return __builtin_amdgcn_cosf(x);   // valid domain +-256 revs; |x| <= ~9 here
#else
    return __cosf(x * 6.2831853071795864f);
#endif
}
__device__ __forceinline__ float fast_rcp(float x) {
#if __has_builtin(__builtin_amdgcn_rcpf)
    return __builtin_amdgcn_rcpf(x);
#else
    return 1.0f / x;
#endif
}

__global__ __launch_bounds__(256, 8) void chirplet_kernel(
    const float* __restrict__ x,
    const float* __restrict__ W,
    const float* __restrict__ Wc,
    const float* __restrict__ S,
    const float* __restrict__ T,
    const float* __restrict__ F,
    const float* __restrict__ bias,
    float* __restrict__ out)
{
    // ~10.4 KB LDS, conflict-free. 16 blocks/CU queued (2x oversubscription —
    // measured better than exact-fit, R6 vs R8). Structure = R9 (best, 74.3us);
    // delta: full i-unroll so the scheduler can hoist a chunk's ds_reads.
    __shared__ __align__(16) float p4_lds[ITILE * P4STRIDE];  // 4 KB  {a,b',c2,d2}
    __shared__ __align__(16) float p2_lds[ITILE * P2STRIDE];  // 2 KB  {lw,w}
    __shared__ __align__(16) float x_lds[ITILE * XSTRIDE];    // 2.125 KB [i][b]
    __shared__ __align__(16) float s_lds[ITILE * XSTRIDE];    // 2.125 KB silu(x)

    const int tid = threadIdx.x;
    const int o0 = blockIdx.x * OTILE;
    const int b0 = blockIdx.y * BTILE;
    const int k0 = blockIdx.z * KCHUNK;

    // compute mapping: thread = (o pair {oc, oc+16}, 4 consecutive b)
    const int oc = tid & 15;        // 0..15
    const int bq = tid >> 4;        // 0..15 -> b = bq*4 + k

    // x staging: 64 b x 8 i = 512 floats, float2 per thread
    const int xrow = tid >> 2;          // 0..63 (b)
    const int xq   = tid & 3;           // col pair: cols 2*xq, 2*xq+1

    // p staging: 32 o x 8 i = 256 (o,i), exactly one per thread
    const int pol = tid & 31;           // o 0..31
    const int pi  = tid >> 5;           // i 0..7

    const float LOG2E = 1.4426950408889634f;
    const float GK    = 0.8493218002880191f;   // sqrt(0.5*log2(e))

    v2f acc2[2][2] = {{{0.f,0.f},{0.f,0.f}},{{0.f,0.f},{0.f,0.f}}};

    for (int c = 0; c < NCHUNKS; ++c) {
        const int ib = k0 + c * ITILE;

        // ---- stage x tile (64 b x 8 i): float2 load, silu, transpose to [i][b]
        {
            const float2 v = *(const float2*)(x + (size_t)(b0 + xrow) * IN_ + ib + xq * 2);
            const float xf[2] = { v.x, v.y };
            #pragma unroll
            for (int j = 0; j < 2; ++j) {
                const int col = xq * 2 + j;
                float xv  = xf[j];
                float sig = fast_rcp(1.0f + fast_exp2(-xv * LOG2E));
                x_lds[col * XSTRIDE + xrow] = xv;
                s_lds[col * XSTRIDE + xrow] = xv * sig;
            }
        }

        // ---- stage params (32 o x 8 i), one per thread; fold coefficients.
        // sign(Wc) -> cos phase (+0.5 rev); |Wc| -> exp2 offset lw = log2|Wc|.
        {
            const size_t go = (size_t)(o0 + pol) * IN_ + ib + pi;
            const float s  = S[go];
            const float t  = T[go];
            const float f  = F[go];
            const float w  = W[go];
            const float wc = Wc[go];
            const float rs = fast_rcp(s);
            const float a  = f * rs;                       // revolutions per x
            float4 p0; float2 p1;
            p0.x = a;
            p0.y = -a * t + (wc < 0.0f ? 0.5f : 0.0f);     // phase offset + sign(Wc)
            p0.z = rs * GK;
            p0.w = -t * rs * GK;
            p1.x = fast_log2(fabsf(wc));                   // lw
            p1.y = w;
            *(float4*)&p4_lds[pi * P4STRIDE + pol * 4] = p0;
            *(float2*)&p2_lds[pi * P2STRIDE + pol * 2] = p1;
        }
        __syncthreads();

        // ---- compute: 4 b x 2 o per thread; FULL unroll (8 i) so all ds_reads
        // of the chunk can be hoisted ahead of dependent trans/fma chains.
        #pragma unroll
        for (int i = 0; i < ITILE; ++i) {
            const float4 abcd[2] = {
                *(const float4*)&p4_lds[i * P4STRIDE + oc * 4],
                *(const float4*)&p4_lds[i * P4STRIDE + (oc + 16) * 4] };
            const float2 lww[2] = {
                *(const float2*)&p2_lds[i * P2STRIDE + oc * 2],
                *(const float2*)&p2_lds[i * P2STRIDE + (oc + 16) * 2] };
            const v2f* xp = (const v2f*)&x_lds[i * XSTRIDE + bq * 4];
            const v2f* sp = (const v2f*)&s_lds[i * XSTRIDE + bq * 4];
            const v2f xk2[2] = { xp[0], xp[1] };
            const v2f sk2[2] = { sp[0], sp[1] };
            #pragma unroll
            for (int o = 0; o < 2; ++o) {
                const v2f aa = { abcd[o].x, abcd[o].x };
                const v2f bb = { abcd[o].y, abcd[o].y };
                const v2f cc = { abcd[o].z, abcd[o].z };
                const v2f dd = { abcd[o].w, abcd[o].w };
                const v2f lw = { lww[o].x, lww[o].x };
                const v2f wv = { lww[o].y, lww[o].y };
                #pragma unroll
                for (int p = 0; p < 2; ++p) {
                    v2f rev = PKFMA(aa, xk2[p], bb);       // phase (revs), packed
                    v2f u   = PKFMA(cc, xk2[p], dd);       // GK*(x-t)/s, packed
                    v2f arg = PKFMA(-u, u, lw);            // lw - u^2, packed
                    v2f co, e;
                    co.x = fast_cos_rev(rev.x);            // trans: 8cyc/wave64 each
                    co.y = fast_cos_rev(rev.y);
                    e.x  = fast_exp2(arg.x);
                    e.y  = fast_exp2(arg.y);
                    acc2[o][p] = PKFMA(co, e, acc2[o][p]); // chirplet, packed
                    acc2[o][p] = PKFMA(sk2[p], wv, acc2[o][p]); // silu*W, packed
                }
            }
        }
        __syncthreads();
    }

    // ---- epilogue: bias (once, from kslice 0) + fp32 atomic accumulate
    const float badd0 = (blockIdx.z == 0) ? bias[o0 + oc] : 0.0f;
    const float badd1 = (blockIdx.z == 0) ? bias[o0 + oc + 16] : 0.0f;
    const float badd[2] = { badd0, badd1 };
    #pragma unroll
    for (int o = 0; o < 2; ++o) {
        #pragma unroll
        for (int p = 0; p < 2; ++p) {
            #pragma unroll
            for (int j = 0; j < 2; ++j) {
                const int b = b0 + bq * 4 + p * 2 + j;
                float* dst = &out[(size_t)b * OUT_ + o0 + oc + o * 16];
                const float val = (j == 0 ? acc2[o][p].x : acc2[o][p].y) + badd[o];
#if defined(__HIP_DEVICE_COMPILE__)
                unsafeAtomicAdd(dst, val);   // HW global_atomic_add_f32
#else
                atomicAdd(dst, val);
#endif
            }
        }
    }
}

extern "C" void kernel_launch(void* const* d_in, const int* in_sizes, int n_in,
                              void* d_out, int out_size, void* d_ws, size_t ws_size,
                              hipStream_t stream) {
    const float* x    = (const float*)d_in[0];
    const float* W    = (const float*)d_in[1];
    const float* Wc   = (const float*)d_in[2];
    const float* S    = (const float*)d_in[3];
    const float* T    = (const float*)d_in[4];
    const float* F    = (const float*)d_in[5];
    const float* bias = (const float*)d_in[6];
    float* out = (float*)d_out;

    // d_out is poisoned before every launch; atomics need zeroed destination
    hipMemsetAsync(out, 0, (size_t)out_size * sizeof(float), stream);

    dim3 grid(OUT_ / OTILE, B_ / BTILE, KSPLIT);   // 16 x 16 x 16 = 4096 blocks
    chirplet_kernel<<<grid, 256, 0, stream>>>(x, W, Wc, S, T, F, bias, out);
}

// Round 14
// 125.248 us; speedup vs baseline: 2.4423x; 1.0482x over previous
//
#include <hip/hip_runtime.h>
#include <hip/hip_bf16.h>

#define B_ 1024
#define IN_ 512
#define OUT_ 512
#define BTILE 64
#define OTILE 32
#define ITILE 8
#define KSPLIT 16
#define KCHUNK (IN_ / KSPLIT)          // 32 i's per block = one MFMA K
#define NCHUNKS (KCHUNK / ITILE)       // 4 staging chunks
#define P4STRIDE 128  // 32 o * 4 words; b128 writes even 8-phase (free); reads 2-way (free)
#define PLSTRIDE 32   // lw: [i][o], reads broadcast/conflict-free
#define XSTRIDE 68    // BTILE + 4 pad; staging writes exactly 2-way (free)
#define ASTRIDE 40    // bf16 per sA/wB row = 80 B (16B-aligned); rows 2-way banks (free)

typedef float v2f   __attribute__((ext_vector_type(2)));
typedef float f32x4 __attribute__((ext_vector_type(4)));
typedef short s16x8 __attribute__((ext_vector_type(8)));   // 8 bf16 = 4 VGPRs
#define PKFMA(a, b, c) __builtin_elementwise_fma((v2f)(a), (v2f)(b), (v2f)(c))

__device__ __forceinline__ unsigned short f2bf(float f) {
    union { float f; unsigned int u; } v; v.f = f;
    unsigned int b = v.u + 0x7FFFu + ((v.u >> 16) & 1u);   // RNE
    return (unsigned short)(b >> 16);
}
__device__ __forceinline__ float fast_exp2(float x) {
#if __has_builtin(__builtin_amdgcn_exp2f)
    return __builtin_amdgcn_exp2f(x);
#else
    return __exp2f(x);
#endif
}
__device__ __forceinline__ float fast_log2(float x) {
#if __has_builtin(__builtin_amdgcn_logf)
    return __builtin_amdgcn_logf(x);
#else
    return __log2f(x);
#endif
}
__device__ __forceinline__ float fast_cos_rev(float x) {  // cos(2*pi*x), revolutions
#if __has_builtin(__builtin_amdgcn_cosf)
    return __builtin_amdgcn_cosf(x);   // valid domain +-256 revs; |x| <= ~9 here
#else
    return __cosf(x * 6.2831853071795864f);
#endif
}
__device__ __forceinline__ float fast_rcp(float x) {
#if __has_builtin(__builtin_amdgcn_rcpf)
    return __builtin_amdgcn_rcpf(x);
#else
    return 1.0f / x;
#endif
}

__global__ __launch_bounds__(256, 8) void chirplet_kernel(
    const float* __restrict__ x,
    const float* __restrict__ W,
    const float* __restrict__ Wc,
    const float* __restrict__ S,
    const float* __restrict__ T,
    const float* __restrict__ F,
    const float* __restrict__ bias,
    float* __restrict__ out)
{
    // Chirplet path on VALU (R9 structure); silu*W GEMM offloaded to the idle
    // matrix pipe. Accumulator mapping (oc=col, bq*4+reg=row) IS the MFMA C/D
    // layout, so MFMA results add register-to-register in the epilogue.
    __shared__ __align__(16) float p4_lds[ITILE * P4STRIDE];   // 4 KB {a,b',c2,d2}
    __shared__ __align__(16) float plw_lds[ITILE * PLSTRIDE];  // 1 KB log2|Wc|
    __shared__ __align__(16) float x_lds[ITILE * XSTRIDE];     // 2.125 KB [i][b]
    __shared__ __align__(16) unsigned short sA_lds[BTILE * ASTRIDE]; // 5 KB silu bf16 [b][k]
    __shared__ __align__(16) unsigned short wB_lds[OTILE * ASTRIDE]; // 2.5 KB W bf16 [o][k]

    const int tid  = threadIdx.x;
    const int wave = tid >> 6;
    const int lane = tid & 63;
    const int o0 = blockIdx.x * OTILE;
    const int b0 = blockIdx.y * BTILE;
    const int k0 = blockIdx.z * KCHUNK;

    const int oc = tid & 15;        // o col
    const int bq = tid >> 4;        // b quad: b = bq*4 + reg  (= MFMA C rows)

    const int xrow = tid >> 2;          // 0..63 (b)
    const int xq   = tid & 3;           // col pair 2*xq, 2*xq+1

    const int pol = tid & 31;           // o 0..31
    const int pi  = tid >> 5;           // i 0..7

    const float LOG2E = 1.4426950408889634f;
    const float GK    = 0.8493218002880191f;   // sqrt(0.5*log2(e))

    v2f acc2[2][2] = {{{0.f,0.f},{0.f,0.f}},{{0.f,0.f},{0.f,0.f}}};

    for (int c = 0; c < NCHUNKS; ++c) {
        const int ib = k0 + c * ITILE;

        // ---- stage x tile: x fp32 -> x_lds[i][b]; silu bf16 -> sA_lds[b][k]
        {
            const float2 v = *(const float2*)(x + (size_t)(b0 + xrow) * IN_ + ib + xq * 2);
            const float xf[2] = { v.x, v.y };
            unsigned int packed = 0;
            #pragma unroll
            for (int j = 0; j < 2; ++j) {
                const int col = xq * 2 + j;
                float xv  = xf[j];
                float sig = fast_rcp(1.0f + fast_exp2(-xv * LOG2E));
                x_lds[col * XSTRIDE + xrow] = xv;
                packed |= (unsigned int)f2bf(xv * sig) << (16 * j);
            }
            *(unsigned int*)&sA_lds[xrow * ASTRIDE + c * 8 + xq * 2] = packed;
        }

        // ---- stage params (32 o x 8 i): chirplet coeffs + W bf16 for MFMA
        {
            const size_t go = (size_t)(o0 + pol) * IN_ + ib + pi;
            const float s  = S[go];
            const float t  = T[go];
            const float f  = F[go];
            const float w  = W[go];
            const float wc = Wc[go];
            const float rs = fast_rcp(s);
            const float a  = f * rs;                       // revolutions per x
            float4 p0;
            p0.x = a;
            p0.y = -a * t + (wc < 0.0f ? 0.5f : 0.0f);     // phase + sign(Wc)
            p0.z = rs * GK;
            p0.w = -t * rs * GK;
            *(float4*)&p4_lds[pi * P4STRIDE + pol * 4] = p0;
            plw_lds[pi * PLSTRIDE + pol] = fast_log2(fabsf(wc));
            wB_lds[pol * ASTRIDE + c * 8 + pi] = f2bf(w);
        }
        __syncthreads();

        // ---- compute: chirplet only (silu*W moved to MFMA). 2 pk-fma-slots/elem.
        #pragma unroll 4
        for (int i = 0; i < ITILE; ++i) {
            const float4 abcd[2] = {
                *(const float4*)&p4_lds[i * P4STRIDE + oc * 4],
                *(const float4*)&p4_lds[i * P4STRIDE + (oc + 16) * 4] };
            const float lw[2] = {
                plw_lds[i * PLSTRIDE + oc],
                plw_lds[i * PLSTRIDE + oc + 16] };
            const v2f* xp = (const v2f*)&x_lds[i * XSTRIDE + bq * 4];
            const v2f xk2[2] = { xp[0], xp[1] };
            #pragma unroll
            for (int o = 0; o < 2; ++o) {
                const v2f aa = { abcd[o].x, abcd[o].x };
                const v2f bb = { abcd[o].y, abcd[o].y };
                const v2f cc = { abcd[o].z, abcd[o].z };
                const v2f dd = { abcd[o].w, abcd[o].w };
                const v2f lwv = { lw[o], lw[o] };
                #pragma unroll
                for (int p = 0; p < 2; ++p) {
                    v2f rev = PKFMA(aa, xk2[p], bb);       // phase (revs)
                    v2f u   = PKFMA(cc, xk2[p], dd);       // GK*(x-t)/s
                    v2f arg = PKFMA(-u, u, lwv);           // lw - u^2
                    v2f co, e;
                    co.x = fast_cos_rev(rev.x);
                    co.y = fast_cos_rev(rev.y);
                    e.x  = fast_exp2(arg.x);
                    e.y  = fast_exp2(arg.y);
                    acc2[o][p] = PKFMA(co, e, acc2[o][p]); // chirplet
                }
            }
        }
        __syncthreads();
    }

    // ---- silu*W via matrix pipe: D[b][o] = sum_k silu[b][k] * W[o][k]
    // A[m=lane&15][k=quad*8+j] from sA (wave's 16 b-rows); B[n=lane&15][k=..] from wB.
    const int q8 = (lane >> 4) * 8;
    const s16x8 af  = *(const s16x8*)&sA_lds[(wave * 16 + (lane & 15)) * ASTRIDE + q8];
    const s16x8 bf0 = *(const s16x8*)&wB_lds[(lane & 15) * ASTRIDE + q8];
    const s16x8 bf1 = *(const s16x8*)&wB_lds[((lane & 15) + 16) * ASTRIDE + q8];
    const f32x4 mz = { 0.f, 0.f, 0.f, 0.f };
    const f32x4 m0 = __builtin_amdgcn_mfma_f32_16x16x32_bf16(af, bf0, mz, 0, 0, 0);
    const f32x4 m1 = __builtin_amdgcn_mfma_f32_16x16x32_bf16(af, bf1, mz, 0, 0, 0);

    // ---- epilogue: chirplet acc + MFMA acc (same C-layout) + bias, atomic add
    const float badd[2] = { (blockIdx.z == 0) ? bias[o0 + oc] : 0.0f,
                            (blockIdx.z == 0) ? bias[o0 + oc + 16] : 0.0f };
    #pragma unroll
    for (int o = 0; o < 2; ++o) {
        #pragma unroll
        for (int p = 0; p < 2; ++p) {
            #pragma unroll
            for (int j = 0; j < 2; ++j) {
                const int reg = p * 2 + j;
                const int b = b0 + bq * 4 + reg;
                float* dst = &out[(size_t)b * OUT_ + o0 + oc + o * 16];
                const float mm = (o == 0) ? m0[reg] : m1[reg];
                const float val = (j == 0 ? acc2[o][p].x : acc2[o][p].y) + mm + badd[o];
#if defined(__HIP_DEVICE_COMPILE__)
                unsafeAtomicAdd(dst, val);   // HW global_atomic_add_f32
#else
                atomicAdd(dst, val);
#endif
            }
        }
    }
}

extern "C" void kernel_launch(void* const* d_in, const int* in_sizes, int n_in,
                              void* d_out, int out_size, void* d_ws, size_t ws_size,
                              hipStream_t stream) {
    const float* x    = (const float*)d_in[0];
    const float* W    = (const float*)d_in[1];
    const float* Wc   = (const float*)d_in[2];
    const float* S    = (const float*)d_in[3];
    const float* T    = (const float*)d_in[4];
    const float* F    = (const float*)d_in[5];
    const float* bias = (const float*)d_in[6];
    float* out = (float*)d_out;

    // d_out is poisoned before every launch; atomics need zeroed destination
    hipMemsetAsync(out, 0, (size_t)out_size * sizeof(float), stream);

    dim3 grid(OUT_ / OTILE, B_ / BTILE, KSPLIT);   // 16 x 16 x 16 = 4096 blocks
    chirplet_kernel<<<grid, 256, 0, stream>>>(x, W, Wc, S, T, F, bias, out);
}